// Round 1
// baseline (3452.624 us; speedup 1.0000x reference)
//
#include <hip/hip_runtime.h>
#include <math.h>

#define HIDDEN 192
#define NBINS 10
#define PROJ 29          // 3*NBINS-1
#define TAILF 5.0f
#define NLAYERS 3
#define NB 64
#define NT 2048
#define TT 64
#define HALO 13
#define COLS (TT + 2*HALO)   // 90
#define CP 91                 // padded (odd) row stride -> conflict-free column access
#define NTB (NT/TT)           // 32
#define LN_EPS 1e-5f
#define MIN_BIN 1e-3f
#define MIN_DERF 1e-3f
#define INV_SQRTF 0.07216878364870323f   // 1/sqrt(192)
#define THREADS 256

// LDS layout (floats)
#define OFF_H 0
#define OFF_Y (HIDDEN*CP)
#define OFF_MK (2*HIDDEN*CP)
#define OFF_FV (OFF_MK + COLS)
#define SMEM_FLOATS (OFF_FV + COLS)
// reuse: projection buffer over yb, spline scratch over hb
#define OFF_PB OFF_Y
#define OFF_SC OFF_H

__device__ __forceinline__ float gelu_exact(float x) {
    return 0.5f * x * (1.0f + erff(x * 0.7071067811865476f));
}
__device__ __forceinline__ float softplus_f(float x) {
    return (x > 20.0f) ? x : log1pf(expf(x));
}
__device__ __forceinline__ float wave_sum(float v) {
    #pragma unroll
    for (int o = 32; o > 0; o >>= 1) v += __shfl_xor(v, o, 64);
    return v;
}

__global__ __launch_bounds__(THREADS) void vits_fused(
    const float* __restrict__ inputs, const float* __restrict__ pmask,
    const float* __restrict__ cpw, const float* __restrict__ cpb,
    const float* __restrict__ dww, const float* __restrict__ dwb,
    const float* __restrict__ pww, const float* __restrict__ pwb,
    const float* __restrict__ g1, const float* __restrict__ b1,
    const float* __restrict__ g2, const float* __restrict__ b2,
    const float* __restrict__ pjw, const float* __restrict__ pjb,
    float* __restrict__ out, float* __restrict__ part)
{
    extern __shared__ float sm[];
    float* hb = sm + OFF_H;
    float* yb = sm + OFF_Y;
    float* mk = sm + OFF_MK;
    float* fv = sm + OFF_FV;

    const int tid = threadIdx.x;
    const int lane = tid & 63;
    const int wid = tid >> 6;
    const int b  = blockIdx.x / NTB;
    const int tb = blockIdx.x % NTB;
    const int t0 = tb*TT - HALO;

    // ---- load first-channel + mask tiles (zero outside [0,T)) ----
    for (int j = tid; j < COLS; j += THREADS) {
        int t = t0 + j;
        bool in = (t >= 0) && (t < NT);
        fv[j] = in ? inputs[(size_t)b*2*NT + t] : 0.0f;
        mk[j] = in ? pmask[(size_t)b*NT + t] : 0.0f;
    }
    __syncthreads();

    // ---- h = conv_pre (outer product, HALF==1) ----
    for (int idx = tid; idx < HIDDEN*COLS; idx += THREADS) {
        int c = idx / COLS, j = idx - c*COLS;
        hb[c*CP + j] = cpw[c]*fv[j] + cpb[c];
    }
    __syncthreads();

    const int dils[NLAYERS]  = {1, 3, 9};
    const int mouts[NLAYERS] = {1, 4, 13};

    for (int L = 0; L < NLAYERS; ++L) {
        const int dil = dils[L];
        const int jlo = mouts[L], jhi = COLS - mouts[L];
        const int nc  = jhi - jlo;

        // ---- depthwise dilated conv + bias (input = h*mask, zero-padded) ----
        for (int idx = tid; idx < HIDDEN*nc; idx += THREADS) {
            int c = idx / nc, j = jlo + (idx - c*nc);
            const float* w = dww + ((size_t)L*HIDDEN + c)*3;
            float v = dwb[L*HIDDEN + c]
                + w[0]*hb[c*CP + j - dil]*mk[j - dil]
                + w[1]*hb[c*CP + j      ]*mk[j      ]
                + w[2]*hb[c*CP + j + dil]*mk[j + dil];
            yb[c*CP + j] = v;
        }
        __syncthreads();

        // ---- LN1 (over channels) + GELU, in place on yb ----
        for (int j = jlo + wid; j < jhi; j += 4) {
            float v0 = yb[(lane      )*CP + j];
            float v1 = yb[(lane + 64 )*CP + j];
            float v2 = yb[(lane + 128)*CP + j];
            float s  = v0 + v1 + v2;
            float ss = v0*v0 + v1*v1 + v2*v2;
            s = wave_sum(s); ss = wave_sum(ss);
            float mu  = s * (1.0f/HIDDEN);
            float var = fmaxf(ss * (1.0f/HIDDEN) - mu*mu, 0.0f);
            float rs  = rsqrtf(var + LN_EPS);
            yb[(lane      )*CP + j] = gelu_exact((v0 - mu)*rs*g1[L*HIDDEN + lane      ] + b1[L*HIDDEN + lane      ]);
            yb[(lane + 64 )*CP + j] = gelu_exact((v1 - mu)*rs*g1[L*HIDDEN + lane + 64 ] + b1[L*HIDDEN + lane + 64 ]);
            yb[(lane + 128)*CP + j] = gelu_exact((v2 - mu)*rs*g1[L*HIDDEN + lane + 128] + b1[L*HIDDEN + lane + 128]);
        }
        __syncthreads();

        // ---- pointwise 192x192 GEMM into register stash ----
        // wave handles 12 o-blocks of 4 rows; lane = column (2 column slots)
        float stash[12][4][2];
        const int j1  = jlo + lane;
        const int j2r = jlo + 64 + lane;
        const int j2  = (j2r < jhi) ? j2r : (jhi - 1);
        #pragma unroll
        for (int q = 0; q < 12; ++q) {
            const int o0 = (wid*12 + q)*4;
            const float* w0 = pww + ((size_t)L*HIDDEN + o0)*HIDDEN;
            float a00=0.f,a01=0.f,a10=0.f,a11=0.f,a20=0.f,a21=0.f,a30=0.f,a31=0.f;
            #pragma unroll 4
            for (int c = 0; c < HIDDEN; ++c) {
                float yA = yb[c*CP + j1];
                float yB = yb[c*CP + j2];
                float wv0 = w0[c];
                float wv1 = w0[HIDDEN   + c];
                float wv2 = w0[2*HIDDEN + c];
                float wv3 = w0[3*HIDDEN + c];
                a00 = fmaf(wv0, yA, a00); a01 = fmaf(wv0, yB, a01);
                a10 = fmaf(wv1, yA, a10); a11 = fmaf(wv1, yB, a11);
                a20 = fmaf(wv2, yA, a20); a21 = fmaf(wv2, yB, a21);
                a30 = fmaf(wv3, yA, a30); a31 = fmaf(wv3, yB, a31);
            }
            stash[q][0][0] = a00 + pwb[L*HIDDEN + o0    ];
            stash[q][0][1] = a01 + pwb[L*HIDDEN + o0    ];
            stash[q][1][0] = a10 + pwb[L*HIDDEN + o0 + 1];
            stash[q][1][1] = a11 + pwb[L*HIDDEN + o0 + 1];
            stash[q][2][0] = a20 + pwb[L*HIDDEN + o0 + 2];
            stash[q][2][1] = a21 + pwb[L*HIDDEN + o0 + 2];
            stash[q][3][0] = a30 + pwb[L*HIDDEN + o0 + 3];
            stash[q][3][1] = a31 + pwb[L*HIDDEN + o0 + 3];
        }
        __syncthreads();   // all reads of yb done
        #pragma unroll
        for (int q = 0; q < 12; ++q) {
            const int o0 = (wid*12 + q)*4;
            #pragma unroll
            for (int r = 0; r < 4; ++r) {
                yb[(o0 + r)*CP + j1] = stash[q][r][0];
                if (j2r < jhi) yb[(o0 + r)*CP + j2r] = stash[q][r][1];
            }
        }
        __syncthreads();

        // ---- LN2 + GELU + residual into hb ----
        for (int j = jlo + wid; j < jhi; j += 4) {
            float v0 = yb[(lane      )*CP + j];
            float v1 = yb[(lane + 64 )*CP + j];
            float v2 = yb[(lane + 128)*CP + j];
            float s  = v0 + v1 + v2;
            float ss = v0*v0 + v1*v1 + v2*v2;
            s = wave_sum(s); ss = wave_sum(ss);
            float mu  = s * (1.0f/HIDDEN);
            float var = fmaxf(ss * (1.0f/HIDDEN) - mu*mu, 0.0f);
            float rs  = rsqrtf(var + LN_EPS);
            hb[(lane      )*CP + j] += gelu_exact((v0 - mu)*rs*g2[L*HIDDEN + lane      ] + b2[L*HIDDEN + lane      ]);
            hb[(lane + 64 )*CP + j] += gelu_exact((v1 - mu)*rs*g2[L*HIDDEN + lane + 64 ] + b2[L*HIDDEN + lane + 64 ]);
            hb[(lane + 128)*CP + j] += gelu_exact((v2 - mu)*rs*g2[L*HIDDEN + lane + 128] + b2[L*HIDDEN + lane + 128]);
        }
        __syncthreads();
    }

    // ---- projection: p[o][j] = proj_w @ (h*mask) + proj_b, o<29, j<64 ----
    float* pb = sm + OFF_PB;   // [TT][33]
    for (int idx = tid; idx < PROJ*TT; idx += THREADS) {
        int o = idx / TT, j = idx - o*TT;
        int jj = HALO + j;
        const float* w = pjw + (size_t)o*HIDDEN;
        float acc = 0.0f;
        #pragma unroll 4
        for (int c = 0; c < HIDDEN; ++c)
            acc = fmaf(w[c], hb[c*CP + jj]*mk[jj], acc);
        pb[j*33 + o] = acc + pjb[o];
    }
    __syncthreads();

    // ---- spline epilogue: one lane per column (wave 0) ----
    float* sc = sm + OFF_SC;   // per-column scratch, stride 57
    if (tid < TT) {
        const int j  = tid;
        const int t  = tb*TT + j;
        const int jj = HALO + j;
        float* S  = sc + j*57;
        float* cw = S;          // 11
        float* ch = S + 11;     // 11
        float* wd = S + 22;     // 10
        float* ht = S + 32;     // 10
        float* dv = S + 42;     // 11

        const float x  = inputs[(size_t)b*2*NT + NT + t];
        const float mv = mk[jj];

        // widths knots from uw = p[0..9] * INV_SQRT
        {
            float u[NBINS]; float m = -1e30f;
            #pragma unroll
            for (int k = 0; k < NBINS; ++k) { u[k] = pb[j*33 + k]*INV_SQRTF; m = fmaxf(m, u[k]); }
            float se = 0.0f;
            #pragma unroll
            for (int k = 0; k < NBINS; ++k) { u[k] = expf(u[k] - m); se += u[k]; }
            float inv = 1.0f/se, csum = 0.0f;
            cw[0] = -TAILF;
            #pragma unroll
            for (int k = 0; k < NBINS; ++k) {
                float wk = MIN_BIN + (1.0f - NBINS*MIN_BIN)*u[k]*inv;
                csum += wk;
                cw[k+1] = 2.0f*TAILF*csum - TAILF;
            }
            cw[NBINS] = TAILF;
            #pragma unroll
            for (int k = 0; k < NBINS; ++k) wd[k] = cw[k+1] - cw[k];
        }
        // heights knots from uh = p[10..19] * INV_SQRT
        {
            float u[NBINS]; float m = -1e30f;
            #pragma unroll
            for (int k = 0; k < NBINS; ++k) { u[k] = pb[j*33 + 10 + k]*INV_SQRTF; m = fmaxf(m, u[k]); }
            float se = 0.0f;
            #pragma unroll
            for (int k = 0; k < NBINS; ++k) { u[k] = expf(u[k] - m); se += u[k]; }
            float inv = 1.0f/se, csum = 0.0f;
            ch[0] = -TAILF;
            #pragma unroll
            for (int k = 0; k < NBINS; ++k) {
                float wk = MIN_BIN + (1.0f - NBINS*MIN_BIN)*u[k]*inv;
                csum += wk;
                ch[k+1] = 2.0f*TAILF*csum - TAILF;
            }
            ch[NBINS] = TAILF;
            #pragma unroll
            for (int k = 0; k < NBINS; ++k) ht[k] = ch[k+1] - ch[k];
        }
        // derivatives (padded with const on both ends)
        {
            const float cpad = logf(expf(1.0f - MIN_DERF) - 1.0f);
            float edge = MIN_DERF + softplus_f(cpad);
            dv[0] = edge;
            #pragma unroll
            for (int k = 0; k < NBINS-1; ++k) dv[k+1] = MIN_DERF + softplus_f(pb[j*33 + 2*NBINS + k]);
            dv[NBINS] = edge;
        }

        const float xi = fminf(fmaxf(x, -TAILF), TAILF);
        int cnt = 0;
        #pragma unroll
        for (int k = 0; k <= NBINS; ++k) {
            float bl = cw[k] + ((k == NBINS) ? 1e-6f : 0.0f);
            cnt += (xi >= bl) ? 1 : 0;
        }
        int bi = cnt - 1;
        bi = (bi < 0) ? 0 : ((bi > NBINS-1) ? NBINS-1 : bi);

        const float in_cw = cw[bi], in_w = wd[bi];
        const float in_ch = ch[bi], in_h = ht[bi];
        const float in_d  = ht[bi]/wd[bi];
        const float dA = dv[bi], dB = dv[bi+1];
        const float i1 = dA + dB - 2.0f*in_d;
        const float th = (xi - in_cw)/in_w;
        const float t1m = th*(1.0f - th);
        const float den = in_d + i1*t1m;
        const float outv = in_ch + in_h*(in_d*th*th + dA*t1m)/den;
        const float omt = 1.0f - th;
        const float dnum = in_d*in_d*(dB*th*th + 2.0f*in_d*t1m + dA*omt*omt);
        const float lad = logf(dnum) - 2.0f*logf(den);

        const bool inside = (x >= -TAILF) && (x <= TAILF);
        const float sec  = inside ? outv : x;
        const float ladm = (inside ? lad : 0.0f) * mv;

        out[(size_t)b*2*NT + t]      = fv[jj]*mv;
        out[(size_t)b*2*NT + NT + t] = sec*mv;

        float tot = wave_sum(ladm);
        if (lane == 0) part[b*NTB + tb] = tot;
    }
}

__global__ void ld_reduce(const float* __restrict__ part, float* __restrict__ ld) {
    int b = threadIdx.x;
    if (b < NB) {
        float s = 0.0f;
        for (int k = 0; k < NTB; ++k) s += part[b*NTB + k];
        ld[b] = s;
    }
}

extern "C" void kernel_launch(void* const* d_in, const int* in_sizes, int n_in,
                              void* d_out, int out_size, void* d_ws, size_t ws_size,
                              hipStream_t stream) {
    const float* inputs = (const float*)d_in[0];
    const float* pmask  = (const float*)d_in[1];
    const float* cpw    = (const float*)d_in[2];
    const float* cpb    = (const float*)d_in[3];
    const float* dww    = (const float*)d_in[4];
    const float* dwb    = (const float*)d_in[5];
    const float* pww    = (const float*)d_in[6];
    const float* pwb    = (const float*)d_in[7];
    const float* g1     = (const float*)d_in[8];
    const float* b1     = (const float*)d_in[9];
    const float* g2     = (const float*)d_in[10];
    const float* b2     = (const float*)d_in[11];
    const float* pjw    = (const float*)d_in[12];
    const float* pjb    = (const float*)d_in[13];
    float* out  = (float*)d_out;
    float* part = (float*)d_ws;

    const size_t smem = (size_t)SMEM_FLOATS * sizeof(float);
    hipFuncSetAttribute(reinterpret_cast<const void*>(vits_fused),
                        hipFuncAttributeMaxDynamicSharedMemorySize, (int)smem);
    vits_fused<<<NB*NTB, THREADS, smem, stream>>>(inputs, pmask, cpw, cpb, dww, dwb,
                                                  pww, pwb, g1, b1, g2, b2, pjw, pjb,
                                                  out, part);
    ld_reduce<<<1, 64, 0, stream>>>(part, out + (size_t)NB*2*NT);
}

// Round 2
// 1683.725 us; speedup vs baseline: 2.0506x; 2.0506x over previous
//
#include <hip/hip_runtime.h>
#include <math.h>

#define HIDDEN 192
#define NBINS 10
#define PROJ 29          // 3*NBINS-1
#define TAILF 5.0f
#define NLAYERS 3
#define NB 64
#define NT 2048
#define TT 64
#define HALO 13
#define COLS (TT + 2*HALO)   // 90
#define CP 91                 // padded (odd) row stride -> conflict-free column access
#define NTB (NT/TT)           // 32
#define LN_EPS 1e-5f
#define MIN_BIN 1e-3f
#define MIN_DERF 1e-3f
#define INV_SQRTF 0.07216878364870323f   // 1/sqrt(192)
#define THREADS 512
#define NWAVES 8
#define ROWS_PER_WAVE (HIDDEN/NWAVES)   // 24

// LDS layout (floats)
#define OFF_H 0
#define OFF_Y (HIDDEN*CP)
#define OFF_MK (2*HIDDEN*CP)
#define OFF_FV (OFF_MK + COLS)
#define SMEM_FLOATS (OFF_FV + COLS)
// reuse: projection buffer over yb, spline scratch over hb
#define OFF_PB OFF_Y
#define OFF_SC OFF_H

__device__ __forceinline__ float gelu_exact(float x) {
    return 0.5f * x * (1.0f + erff(x * 0.7071067811865476f));
}
__device__ __forceinline__ float softplus_f(float x) {
    return (x > 20.0f) ? x : log1pf(expf(x));
}
__device__ __forceinline__ float wave_sum(float v) {
    #pragma unroll
    for (int o = 32; o > 0; o >>= 1) v += __shfl_xor(v, o, 64);
    return v;
}

__global__ __launch_bounds__(THREADS) void vits_fused(
    const float* __restrict__ inputs, const float* __restrict__ pmask,
    const float* __restrict__ cpw, const float* __restrict__ cpb,
    const float* __restrict__ dww, const float* __restrict__ dwb,
    const float* __restrict__ pww, const float* __restrict__ pwb,
    const float* __restrict__ g1, const float* __restrict__ b1,
    const float* __restrict__ g2, const float* __restrict__ b2,
    const float* __restrict__ pjw, const float* __restrict__ pjb,
    float* __restrict__ out, float* __restrict__ part)
{
    extern __shared__ float sm[];
    float* hb = sm + OFF_H;
    float* yb = sm + OFF_Y;
    float* mk = sm + OFF_MK;
    float* fv = sm + OFF_FV;

    const int tid = threadIdx.x;
    const int lane = tid & 63;
    const int wid = tid >> 6;
    const int wu  = __builtin_amdgcn_readfirstlane(wid);   // wave-uniform wave id (SGPR)
    const int b  = blockIdx.x / NTB;
    const int tb = blockIdx.x % NTB;
    const int t0 = tb*TT - HALO;

    // ---- load first-channel + mask tiles (zero outside [0,T)) ----
    for (int j = tid; j < COLS; j += THREADS) {
        int t = t0 + j;
        bool in = (t >= 0) && (t < NT);
        fv[j] = in ? inputs[(size_t)b*2*NT + t] : 0.0f;
        mk[j] = in ? pmask[(size_t)b*NT + t] : 0.0f;
    }
    __syncthreads();

    // ---- h = conv_pre (outer product, HALF==1), row-per-wave -> scalar weights ----
    for (int c = wu; c < HIDDEN; c += NWAVES) {
        const float wv = cpw[c], bv = cpb[c];
        float* hrow = hb + c*CP;
        for (int j = lane; j < COLS; j += 64)
            hrow[j] = wv*fv[j] + bv;
    }
    __syncthreads();

    const int dils[NLAYERS]  = {1, 3, 9};
    const int mouts[NLAYERS] = {1, 4, 13};

    for (int L = 0; L < NLAYERS; ++L) {
        const int dil = dils[L];
        const int jlo = mouts[L], jhi = COLS - mouts[L];

        // ---- depthwise dilated conv + bias, row-per-wave (scalar weights) ----
        for (int c = wu; c < HIDDEN; c += NWAVES) {
            const float* w = dww + ((size_t)L*HIDDEN + c)*3;
            const float w0 = w[0], w1 = w[1], w2 = w[2];
            const float bv = dwb[L*HIDDEN + c];
            const float* hrow = hb + c*CP;
            float* yrow = yb + c*CP;
            for (int j = jlo + lane; j < jhi; j += 64) {
                yrow[j] = bv + w0*hrow[j-dil]*mk[j-dil]
                             + w1*hrow[j    ]*mk[j    ]
                             + w2*hrow[j+dil]*mk[j+dil];
            }
        }
        __syncthreads();

        // ---- LN1 (over channels) + GELU, in place on yb ----
        {
            const float ga0 = g1[L*HIDDEN + lane      ], bb0 = b1[L*HIDDEN + lane      ];
            const float ga1 = g1[L*HIDDEN + lane + 64 ], bb1 = b1[L*HIDDEN + lane + 64 ];
            const float ga2 = g1[L*HIDDEN + lane + 128], bb2 = b1[L*HIDDEN + lane + 128];
            for (int j = jlo + wu; j < jhi; j += NWAVES) {
                float v0 = yb[(lane      )*CP + j];
                float v1 = yb[(lane + 64 )*CP + j];
                float v2 = yb[(lane + 128)*CP + j];
                float s  = v0 + v1 + v2;
                float ss = v0*v0 + v1*v1 + v2*v2;
                s = wave_sum(s); ss = wave_sum(ss);
                float mu  = s * (1.0f/HIDDEN);
                float var = fmaxf(ss * (1.0f/HIDDEN) - mu*mu, 0.0f);
                float rs  = rsqrtf(var + LN_EPS);
                yb[(lane      )*CP + j] = gelu_exact((v0 - mu)*rs*ga0 + bb0);
                yb[(lane + 64 )*CP + j] = gelu_exact((v1 - mu)*rs*ga1 + bb1);
                yb[(lane + 128)*CP + j] = gelu_exact((v2 - mu)*rs*ga2 + bb2);
            }
        }
        __syncthreads();

        // ---- pointwise 192x192 GEMM: c-outer, scalar weight loads ----
        {
            const int o0 = wu * ROWS_PER_WAVE;
            const float* wbase = pww + (size_t)L*HIDDEN*HIDDEN + (size_t)o0*HIDDEN;
            const float* bbase = pwb + L*HIDDEN + o0;
            const int j1  = jlo + lane;
            const int j2r = jlo + 64 + lane;
            const bool hasB = (jlo + 64) < jhi;   // uniform
            const int j2  = (j2r < jhi) ? j2r : (jhi - 1);

            float accA[ROWS_PER_WAVE], accB[ROWS_PER_WAVE];
            #pragma unroll
            for (int r = 0; r < ROWS_PER_WAVE; ++r) { accA[r] = 0.0f; accB[r] = 0.0f; }

            if (hasB) {
                #pragma unroll 2
                for (int c = 0; c < HIDDEN; ++c) {
                    const float yA = yb[c*CP + j1];
                    const float yB = yb[c*CP + j2];
                    #pragma unroll
                    for (int r = 0; r < ROWS_PER_WAVE; ++r) {
                        const float wv = wbase[(size_t)r*HIDDEN + c];   // SGPR-uniform -> s_load
                        accA[r] = fmaf(wv, yA, accA[r]);
                        accB[r] = fmaf(wv, yB, accB[r]);
                    }
                }
            } else {
                #pragma unroll 2
                for (int c = 0; c < HIDDEN; ++c) {
                    const float yA = yb[c*CP + j1];
                    #pragma unroll
                    for (int r = 0; r < ROWS_PER_WAVE; ++r) {
                        const float wv = wbase[(size_t)r*HIDDEN + c];
                        accA[r] = fmaf(wv, yA, accA[r]);
                    }
                }
            }
            __syncthreads();   // all reads of yb done
            #pragma unroll
            for (int r = 0; r < ROWS_PER_WAVE; ++r) {
                const float bv = bbase[r];
                yb[(o0 + r)*CP + j1] = accA[r] + bv;
                if (hasB && j2r < jhi) yb[(o0 + r)*CP + j2r] = accB[r] + bv;
            }
        }
        __syncthreads();

        // ---- LN2 + GELU + residual into hb ----
        {
            const float ga0 = g2[L*HIDDEN + lane      ], bb0 = b2[L*HIDDEN + lane      ];
            const float ga1 = g2[L*HIDDEN + lane + 64 ], bb1 = b2[L*HIDDEN + lane + 64 ];
            const float ga2 = g2[L*HIDDEN + lane + 128], bb2 = b2[L*HIDDEN + lane + 128];
            for (int j = jlo + wu; j < jhi; j += NWAVES) {
                float v0 = yb[(lane      )*CP + j];
                float v1 = yb[(lane + 64 )*CP + j];
                float v2 = yb[(lane + 128)*CP + j];
                float s  = v0 + v1 + v2;
                float ss = v0*v0 + v1*v1 + v2*v2;
                s = wave_sum(s); ss = wave_sum(ss);
                float mu  = s * (1.0f/HIDDEN);
                float var = fmaxf(ss * (1.0f/HIDDEN) - mu*mu, 0.0f);
                float rs  = rsqrtf(var + LN_EPS);
                hb[(lane      )*CP + j] += gelu_exact((v0 - mu)*rs*ga0 + bb0);
                hb[(lane + 64 )*CP + j] += gelu_exact((v1 - mu)*rs*ga1 + bb1);
                hb[(lane + 128)*CP + j] += gelu_exact((v2 - mu)*rs*ga2 + bb2);
            }
        }
        __syncthreads();
    }

    // ---- projection: p[o][j] = proj_w @ (h*mask) + proj_b, o<29, j<64 ----
    float* pb = sm + OFF_PB;   // [TT][33]
    for (int idx = tid; idx < PROJ*TT; idx += THREADS) {
        int o = __builtin_amdgcn_readfirstlane(idx >> 6);  // TT==64 -> o wave-uniform
        int j = idx & 63;
        int jj = HALO + j;
        const float* w = pjw + (size_t)o*HIDDEN;
        const float mkv = mk[jj];
        float acc = 0.0f;
        #pragma unroll 4
        for (int c = 0; c < HIDDEN; ++c)
            acc = fmaf(w[c], hb[c*CP + jj], acc);
        pb[j*33 + o] = acc*mkv + pjb[o];
    }
    __syncthreads();

    // ---- spline epilogue: one lane per column (wave 0) ----
    float* sc = sm + OFF_SC;   // per-column scratch, stride 57
    if (tid < TT) {
        const int j  = tid;
        const int t  = tb*TT + j;
        const int jj = HALO + j;
        float* S  = sc + j*57;
        float* cw = S;          // 11
        float* ch = S + 11;     // 11
        float* wd = S + 22;     // 10
        float* ht = S + 32;     // 10
        float* dv = S + 42;     // 11

        const float x  = inputs[(size_t)b*2*NT + NT + t];
        const float mv = mk[jj];

        // widths knots from uw = p[0..9] * INV_SQRT
        {
            float u[NBINS]; float m = -1e30f;
            #pragma unroll
            for (int k = 0; k < NBINS; ++k) { u[k] = pb[j*33 + k]*INV_SQRTF; m = fmaxf(m, u[k]); }
            float se = 0.0f;
            #pragma unroll
            for (int k = 0; k < NBINS; ++k) { u[k] = expf(u[k] - m); se += u[k]; }
            float inv = 1.0f/se, csum = 0.0f;
            cw[0] = -TAILF;
            #pragma unroll
            for (int k = 0; k < NBINS; ++k) {
                float wk = MIN_BIN + (1.0f - NBINS*MIN_BIN)*u[k]*inv;
                csum += wk;
                cw[k+1] = 2.0f*TAILF*csum - TAILF;
            }
            cw[NBINS] = TAILF;
            #pragma unroll
            for (int k = 0; k < NBINS; ++k) wd[k] = cw[k+1] - cw[k];
        }
        // heights knots from uh = p[10..19] * INV_SQRT
        {
            float u[NBINS]; float m = -1e30f;
            #pragma unroll
            for (int k = 0; k < NBINS; ++k) { u[k] = pb[j*33 + 10 + k]*INV_SQRTF; m = fmaxf(m, u[k]); }
            float se = 0.0f;
            #pragma unroll
            for (int k = 0; k < NBINS; ++k) { u[k] = expf(u[k] - m); se += u[k]; }
            float inv = 1.0f/se, csum = 0.0f;
            ch[0] = -TAILF;
            #pragma unroll
            for (int k = 0; k < NBINS; ++k) {
                float wk = MIN_BIN + (1.0f - NBINS*MIN_BIN)*u[k]*inv;
                csum += wk;
                ch[k+1] = 2.0f*TAILF*csum - TAILF;
            }
            ch[NBINS] = TAILF;
            #pragma unroll
            for (int k = 0; k < NBINS; ++k) ht[k] = ch[k+1] - ch[k];
        }
        // derivatives (padded with const on both ends)
        {
            const float cpad = logf(expf(1.0f - MIN_DERF) - 1.0f);
            float edge = MIN_DERF + softplus_f(cpad);
            dv[0] = edge;
            #pragma unroll
            for (int k = 0; k < NBINS-1; ++k) dv[k+1] = MIN_DERF + softplus_f(pb[j*33 + 2*NBINS + k]);
            dv[NBINS] = edge;
        }

        const float xi = fminf(fmaxf(x, -TAILF), TAILF);
        int cnt = 0;
        #pragma unroll
        for (int k = 0; k <= NBINS; ++k) {
            float bl = cw[k] + ((k == NBINS) ? 1e-6f : 0.0f);
            cnt += (xi >= bl) ? 1 : 0;
        }
        int bi = cnt - 1;
        bi = (bi < 0) ? 0 : ((bi > NBINS-1) ? NBINS-1 : bi);

        const float in_cw = cw[bi], in_w = wd[bi];
        const float in_ch = ch[bi], in_h = ht[bi];
        const float in_d  = ht[bi]/wd[bi];
        const float dA = dv[bi], dB = dv[bi+1];
        const float i1 = dA + dB - 2.0f*in_d;
        const float th = (xi - in_cw)/in_w;
        const float t1m = th*(1.0f - th);
        const float den = in_d + i1*t1m;
        const float outv = in_ch + in_h*(in_d*th*th + dA*t1m)/den;
        const float omt = 1.0f - th;
        const float dnum = in_d*in_d*(dB*th*th + 2.0f*in_d*t1m + dA*omt*omt);
        const float lad = logf(dnum) - 2.0f*logf(den);

        const bool inside = (x >= -TAILF) && (x <= TAILF);
        const float sec  = inside ? outv : x;
        const float ladm = (inside ? lad : 0.0f) * mv;

        out[(size_t)b*2*NT + t]      = fv[jj]*mv;
        out[(size_t)b*2*NT + NT + t] = sec*mv;

        float tot = wave_sum(ladm);
        if (lane == 0) part[b*NTB + tb] = tot;
    }
}

__global__ void ld_reduce(const float* __restrict__ part, float* __restrict__ ld) {
    int b = threadIdx.x;
    if (b < NB) {
        float s = 0.0f;
        for (int k = 0; k < NTB; ++k) s += part[b*NTB + k];
        ld[b] = s;
    }
}

extern "C" void kernel_launch(void* const* d_in, const int* in_sizes, int n_in,
                              void* d_out, int out_size, void* d_ws, size_t ws_size,
                              hipStream_t stream) {
    const float* inputs = (const float*)d_in[0];
    const float* pmask  = (const float*)d_in[1];
    const float* cpw    = (const float*)d_in[2];
    const float* cpb    = (const float*)d_in[3];
    const float* dww    = (const float*)d_in[4];
    const float* dwb    = (const float*)d_in[5];
    const float* pww    = (const float*)d_in[6];
    const float* pwb    = (const float*)d_in[7];
    const float* g1     = (const float*)d_in[8];
    const float* b1     = (const float*)d_in[9];
    const float* g2     = (const float*)d_in[10];
    const float* b2     = (const float*)d_in[11];
    const float* pjw    = (const float*)d_in[12];
    const float* pjb    = (const float*)d_in[13];
    float* out  = (float*)d_out;
    float* part = (float*)d_ws;

    const size_t smem = (size_t)SMEM_FLOATS * sizeof(float);
    hipFuncSetAttribute(reinterpret_cast<const void*>(vits_fused),
                        hipFuncAttributeMaxDynamicSharedMemorySize, (int)smem);
    vits_fused<<<NB*NTB, THREADS, smem, stream>>>(inputs, pmask, cpw, cpb, dww, dwb,
                                                  pww, pwb, g1, b1, g2, b2, pjw, pjb,
                                                  out, part);
    ld_reduce<<<1, 64, 0, stream>>>(part, out + (size_t)NB*2*NT);
}

// Round 3
// 858.195 us; speedup vs baseline: 4.0231x; 1.9619x over previous
//
#include <hip/hip_runtime.h>
#include <math.h>

#define HIDDEN 192
#define NBINS 10
#define PROJ 29          // 3*NBINS-1
#define TAILF 5.0f
#define NLAYERS 3
#define NB 64
#define NT 2048
#define TT 64
#define HALO 13
#define COLS (TT + 2*HALO)   // 90
#define CP 91                 // padded f32 row stride (odd dwords)
#define NPAD 96               // GEMM N padded
#define YS 194                // Yt bf16 row stride (= 97 dwords, odd -> conflict-free)
#define NTB (NT/TT)           // 32
#define LN_EPS 1e-5f
#define MIN_BIN 1e-3f
#define MIN_DERF 1e-3f
#define INV_SQRTF 0.07216878364870323f   // 1/sqrt(192)
#define THREADS 768
#define NWAVES 12

// LDS layout (float units)
#define OFF_H 0
#define OFF_YT (HIDDEN*CP)                    // 17472
#define YT_FLOATS (NPAD*YS/2)                 // 9312
#define OFF_MK (OFF_YT + YT_FLOATS)           // 26784
#define OFF_FV (OFF_MK + COLS)
#define SMEM_FLOATS (OFF_FV + COLS)           // 26964 floats = 107856 B
#define OFF_PB OFF_YT                         // projection buffer reuses Yt
#define OFF_SC OFF_H                          // spline scratch reuses hb

typedef __attribute__((ext_vector_type(8))) short bf16x8;
typedef __attribute__((ext_vector_type(4))) float f32x4;

__device__ __forceinline__ float gelu_exact(float x) {
    return 0.5f * x * (1.0f + erff(x * 0.7071067811865476f));
}
__device__ __forceinline__ float softplus_f(float x) {
    return (x > 20.0f) ? x : log1pf(expf(x));
}
__device__ __forceinline__ float wave_sum(float v) {
    #pragma unroll
    for (int o = 32; o > 0; o >>= 1) v += __shfl_xor(v, o, 64);
    return v;
}
__device__ __forceinline__ unsigned short f2bf(float f) {
    union { float f; unsigned u; } c; c.f = f;
    unsigned r = c.u + 0x7FFFu + ((c.u >> 16) & 1u);
    return (unsigned short)(r >> 16);
}
__device__ __forceinline__ float bf2f_lo(unsigned u) {
    union { unsigned u; float f; } c; c.u = u << 16; return c.f;
}
__device__ __forceinline__ float bf2f_hi(unsigned u) {
    union { unsigned u; float f; } c; c.u = u & 0xffff0000u; return c.f;
}

// LN over channels for one column (8 lanes/col, 24 ch/lane) + GELU.
// toYt: write result back to Yt (bf16). else: residual-add into hb (f32), predicated on col range.
__device__ __forceinline__ void ln_pass(unsigned short* yt, float* hb,
                                        const float* g, const float* b,
                                        int tid, int jlo, int jhi, bool toYt) {
    const int col = tid >> 3, q = tid & 7;
    const int c0 = q * 24;
    unsigned short* row = yt + col * YS;
    const unsigned* rp = (const unsigned*)(row + c0);
    float v[24];
    float s = 0.0f, ss = 0.0f;
    #pragma unroll
    for (int i = 0; i < 12; ++i) {
        unsigned u = rp[i];
        float a = bf2f_lo(u), c = bf2f_hi(u);
        v[2*i] = a; v[2*i+1] = c;
        s += a + c; ss += a*a + c*c;
    }
    s  += __shfl_xor(s, 1, 64);  s  += __shfl_xor(s, 2, 64);  s  += __shfl_xor(s, 4, 64);
    ss += __shfl_xor(ss, 1, 64); ss += __shfl_xor(ss, 2, 64); ss += __shfl_xor(ss, 4, 64);
    const float mu  = s * (1.0f/HIDDEN);
    const float var = fmaxf(ss * (1.0f/HIDDEN) - mu*mu, 0.0f);
    const float rs  = rsqrtf(var + LN_EPS);

    float gv[24], bv[24];
    #pragma unroll
    for (int i = 0; i < 6; ++i) {
        float4 t = *(const float4*)(g + c0 + 4*i);
        gv[4*i] = t.x; gv[4*i+1] = t.y; gv[4*i+2] = t.z; gv[4*i+3] = t.w;
        float4 u = *(const float4*)(b + c0 + 4*i);
        bv[4*i] = u.x; bv[4*i+1] = u.y; bv[4*i+2] = u.z; bv[4*i+3] = u.w;
    }
    if (toYt) {
        unsigned* wp = (unsigned*)(row + c0);
        #pragma unroll
        for (int i = 0; i < 12; ++i) {
            float r0 = gelu_exact((v[2*i]   - mu)*rs*gv[2*i]   + bv[2*i]);
            float r1 = gelu_exact((v[2*i+1] - mu)*rs*gv[2*i+1] + bv[2*i+1]);
            wp[i] = (unsigned)f2bf(r0) | ((unsigned)f2bf(r1) << 16);
        }
    } else {
        if (col >= jlo && col < jhi) {
            #pragma unroll
            for (int i = 0; i < 24; ++i) {
                float r = gelu_exact((v[i] - mu)*rs*gv[i] + bv[i]);
                hb[(c0 + i)*CP + col] += r;
            }
        }
    }
}

__global__ __launch_bounds__(THREADS) void vits_fused(
    const float* __restrict__ inputs, const float* __restrict__ pmask,
    const float* __restrict__ cpw, const float* __restrict__ cpb,
    const float* __restrict__ dww, const float* __restrict__ dwb,
    const float* __restrict__ pww, const float* __restrict__ pwb,
    const float* __restrict__ g1, const float* __restrict__ b1,
    const float* __restrict__ g2, const float* __restrict__ b2,
    const float* __restrict__ pjw, const float* __restrict__ pjb,
    float* __restrict__ out, float* __restrict__ part)
{
    extern __shared__ float sm[];
    float* hb = sm + OFF_H;
    unsigned short* yt = (unsigned short*)(sm + OFF_YT);
    float* mk = sm + OFF_MK;
    float* fv = sm + OFF_FV;

    const int tid = threadIdx.x;
    const int lane = tid & 63;
    const int wid = tid >> 6;
    const int wu  = __builtin_amdgcn_readfirstlane(wid);
    const int b  = blockIdx.x / NTB;
    const int tb = blockIdx.x % NTB;
    const int t0 = tb*TT - HALO;

    // ---- load first-channel + mask tiles (zero outside [0,T)) ----
    for (int j = tid; j < COLS; j += THREADS) {
        int t = t0 + j;
        bool in = (t >= 0) && (t < NT);
        fv[j] = in ? inputs[(size_t)b*2*NT + t] : 0.0f;
        mk[j] = in ? pmask[(size_t)b*NT + t] : 0.0f;
    }
    __syncthreads();

    // ---- h = conv_pre (outer product, HALF==1), row-per-wave ----
    for (int c = wu; c < HIDDEN; c += NWAVES) {
        const float wv = cpw[c], bv = cpb[c];
        float* hrow = hb + c*CP;
        for (int j = lane; j < COLS; j += 64)
            hrow[j] = wv*fv[j] + bv;
    }
    __syncthreads();

    const int dils[NLAYERS]  = {1, 3, 9};
    const int mouts[NLAYERS] = {1, 4, 13};

    const int l15 = lane & 15, hi = lane >> 4;
    const int mgrp = wu & 3;    // 0..3 -> M offset mgrp*48 (3 M-tiles)
    const int ngrp = wu >> 2;   // 0..2 -> N offset ngrp*32 (2 N-tiles)

    for (int L = 0; L < NLAYERS; ++L) {
        const int dil = dils[L];
        const int jlo = mouts[L], jhi = COLS - mouts[L];

        // ---- depthwise dilated conv + bias -> Yt (bf16, transposed); dead cols zeroed ----
        for (int c = wu; c < HIDDEN; c += NWAVES) {
            const float* w = dww + ((size_t)L*HIDDEN + c)*3;
            const float w0 = w[0], w1 = w[1], w2 = w[2];
            const float bv = dwb[L*HIDDEN + c];
            const float* hrow = hb + c*CP;
            for (int jj = lane; jj < NPAD; jj += 64) {
                float v = 0.0f;
                if (jj >= jlo && jj < jhi)
                    v = bv + w0*hrow[jj-dil]*mk[jj-dil]
                           + w1*hrow[jj    ]*mk[jj    ]
                           + w2*hrow[jj+dil]*mk[jj+dil];
                yt[jj*YS + c] = f2bf(v);
            }
        }
        __syncthreads();

        // ---- LN1 + GELU in place on Yt ----
        ln_pass(yt, hb, g1 + L*HIDDEN, b1 + L*HIDDEN, tid, jlo, jhi, true);
        __syncthreads();

        // ---- pointwise 192x192 GEMM via MFMA (bf16 in, f32 acc) ----
        {
            // B fragments: Yt rows = columns n, contiguous k
            bf16x8 Bf[2][6];
            #pragma unroll
            for (int nt = 0; nt < 2; ++nt) {
                const int n = ngrp*32 + nt*16 + l15;
                const unsigned short* yr = yt + n*YS;
                #pragma unroll
                for (int ks = 0; ks < 6; ++ks) {
                    const unsigned* p = (const unsigned*)(yr + ks*32 + hi*8);
                    unsigned u0 = p[0], u1 = p[1], u2 = p[2], u3 = p[3];
                    bf16x8 t;
                    t[0] = (short)(u0 & 0xffff); t[1] = (short)(u0 >> 16);
                    t[2] = (short)(u1 & 0xffff); t[3] = (short)(u1 >> 16);
                    t[4] = (short)(u2 & 0xffff); t[5] = (short)(u2 >> 16);
                    t[6] = (short)(u3 & 0xffff); t[7] = (short)(u3 >> 16);
                    Bf[nt][ks] = t;
                }
            }
            f32x4 acc[3][2];
            #pragma unroll
            for (int mt = 0; mt < 3; ++mt)
                #pragma unroll
                for (int nt = 0; nt < 2; ++nt)
                    acc[mt][nt] = (f32x4){0.0f, 0.0f, 0.0f, 0.0f};

            const float* wlayer = pww + (size_t)L*HIDDEN*HIDDEN;
            #pragma unroll
            for (int mt = 0; mt < 3; ++mt) {
                const int m = mgrp*48 + mt*16 + l15;
                const float* wr = wlayer + (size_t)m*HIDDEN + hi*8;
                #pragma unroll
                for (int ks = 0; ks < 6; ++ks) {
                    float4 a0 = *(const float4*)(wr + ks*32);
                    float4 a1 = *(const float4*)(wr + ks*32 + 4);
                    bf16x8 a;
                    a[0] = (short)f2bf(a0.x); a[1] = (short)f2bf(a0.y);
                    a[2] = (short)f2bf(a0.z); a[3] = (short)f2bf(a0.w);
                    a[4] = (short)f2bf(a1.x); a[5] = (short)f2bf(a1.y);
                    a[6] = (short)f2bf(a1.z); a[7] = (short)f2bf(a1.w);
                    acc[mt][0] = __builtin_amdgcn_mfma_f32_16x16x32_bf16(a, Bf[0][ks], acc[mt][0], 0, 0, 0);
                    acc[mt][1] = __builtin_amdgcn_mfma_f32_16x16x32_bf16(a, Bf[1][ks], acc[mt][1], 0, 0, 0);
                }
            }
            __syncthreads();   // all Yt reads complete before overwrite

            // bias + write z back over Yt (bf16, transposed)
            #pragma unroll
            for (int mt = 0; mt < 3; ++mt) {
                const int mrow = mgrp*48 + mt*16 + hi*4;
                float4 bias = *(const float4*)(pwb + L*HIDDEN + mrow);
                #pragma unroll
                for (int nt = 0; nt < 2; ++nt) {
                    const int n = ngrp*32 + nt*16 + l15;
                    unsigned* zr = (unsigned*)(yt + n*YS + mrow);
                    f32x4 v = acc[mt][nt];
                    zr[0] = (unsigned)f2bf(v[0] + bias.x) | ((unsigned)f2bf(v[1] + bias.y) << 16);
                    zr[1] = (unsigned)f2bf(v[2] + bias.z) | ((unsigned)f2bf(v[3] + bias.w) << 16);
                }
            }
        }
        __syncthreads();

        // ---- LN2 + GELU + residual into hb (f32) ----
        ln_pass(yt, hb, g2 + L*HIDDEN, b2 + L*HIDDEN, tid, jlo, jhi, false);
        __syncthreads();
    }

    // ---- projection: p[o][j] = proj_w @ (h*mask) + proj_b, o<29, j<64 ----
    float* pb = sm + OFF_PB;   // [TT][33]
    for (int idx = tid; idx < PROJ*TT; idx += THREADS) {
        int o = __builtin_amdgcn_readfirstlane(idx >> 6);  // uniform per wave
        int j = idx & 63;
        int jj = HALO + j;
        const float* w = pjw + (size_t)o*HIDDEN;
        const float mkv = mk[jj];
        float acc = 0.0f;
        #pragma unroll 4
        for (int c = 0; c < HIDDEN; ++c)
            acc = fmaf(w[c], hb[c*CP + jj], acc);
        pb[j*33 + o] = acc*mkv + pjb[o];
    }
    __syncthreads();

    // ---- spline epilogue: one lane per column (wave 0) ----
    float* sc = sm + OFF_SC;
    if (tid < TT) {
        const int j  = tid;
        const int t  = tb*TT + j;
        const int jj = HALO + j;
        float* S  = sc + j*57;
        float* cw = S;          // 11
        float* ch = S + 11;     // 11
        float* wd = S + 22;     // 10
        float* ht = S + 32;     // 10
        float* dv = S + 42;     // 11

        const float x  = inputs[(size_t)b*2*NT + NT + t];
        const float mv = mk[jj];

        {
            float u[NBINS]; float m = -1e30f;
            #pragma unroll
            for (int k = 0; k < NBINS; ++k) { u[k] = pb[j*33 + k]*INV_SQRTF; m = fmaxf(m, u[k]); }
            float se = 0.0f;
            #pragma unroll
            for (int k = 0; k < NBINS; ++k) { u[k] = expf(u[k] - m); se += u[k]; }
            float inv = 1.0f/se, csum = 0.0f;
            cw[0] = -TAILF;
            #pragma unroll
            for (int k = 0; k < NBINS; ++k) {
                float wk = MIN_BIN + (1.0f - NBINS*MIN_BIN)*u[k]*inv;
                csum += wk;
                cw[k+1] = 2.0f*TAILF*csum - TAILF;
            }
            cw[NBINS] = TAILF;
            #pragma unroll
            for (int k = 0; k < NBINS; ++k) wd[k] = cw[k+1] - cw[k];
        }
        {
            float u[NBINS]; float m = -1e30f;
            #pragma unroll
            for (int k = 0; k < NBINS; ++k) { u[k] = pb[j*33 + 10 + k]*INV_SQRTF; m = fmaxf(m, u[k]); }
            float se = 0.0f;
            #pragma unroll
            for (int k = 0; k < NBINS; ++k) { u[k] = expf(u[k] - m); se += u[k]; }
            float inv = 1.0f/se, csum = 0.0f;
            ch[0] = -TAILF;
            #pragma unroll
            for (int k = 0; k < NBINS; ++k) {
                float wk = MIN_BIN + (1.0f - NBINS*MIN_BIN)*u[k]*inv;
                csum += wk;
                ch[k+1] = 2.0f*TAILF*csum - TAILF;
            }
            ch[NBINS] = TAILF;
            #pragma unroll
            for (int k = 0; k < NBINS; ++k) ht[k] = ch[k+1] - ch[k];
        }
        {
            const float cpad = logf(expf(1.0f - MIN_DERF) - 1.0f);
            float edge = MIN_DERF + softplus_f(cpad);
            dv[0] = edge;
            #pragma unroll
            for (int k = 0; k < NBINS-1; ++k) dv[k+1] = MIN_DERF + softplus_f(pb[j*33 + 2*NBINS + k]);
            dv[NBINS] = edge;
        }

        const float xi = fminf(fmaxf(x, -TAILF), TAILF);
        int cnt = 0;
        #pragma unroll
        for (int k = 0; k <= NBINS; ++k) {
            float bl = cw[k] + ((k == NBINS) ? 1e-6f : 0.0f);
            cnt += (xi >= bl) ? 1 : 0;
        }
        int bi = cnt - 1;
        bi = (bi < 0) ? 0 : ((bi > NBINS-1) ? NBINS-1 : bi);

        const float in_cw = cw[bi], in_w = wd[bi];
        const float in_ch = ch[bi], in_h = ht[bi];
        const float in_d  = ht[bi]/wd[bi];
        const float dA = dv[bi], dB = dv[bi+1];
        const float i1 = dA + dB - 2.0f*in_d;
        const float th = (xi - in_cw)/in_w;
        const float t1m = th*(1.0f - th);
        const float den = in_d + i1*t1m;
        const float outv = in_ch + in_h*(in_d*th*th + dA*t1m)/den;
        const float omt = 1.0f - th;
        const float dnum = in_d*in_d*(dB*th*th + 2.0f*in_d*t1m + dA*omt*omt);
        const float lad = logf(dnum) - 2.0f*logf(den);

        const bool inside = (x >= -TAILF) && (x <= TAILF);
        const float sec  = inside ? outv : x;
        const float ladm = (inside ? lad : 0.0f) * mv;

        out[(size_t)b*2*NT + t]      = fv[jj]*mv;
        out[(size_t)b*2*NT + NT + t] = sec*mv;

        float tot = wave_sum(ladm);
        if (lane == 0) part[b*NTB + tb] = tot;
    }
}

__global__ void ld_reduce(const float* __restrict__ part, float* __restrict__ ld) {
    int b = threadIdx.x;
    if (b < NB) {
        float s = 0.0f;
        for (int k = 0; k < NTB; ++k) s += part[b*NTB + k];
        ld[b] = s;
    }
}

extern "C" void kernel_launch(void* const* d_in, const int* in_sizes, int n_in,
                              void* d_out, int out_size, void* d_ws, size_t ws_size,
                              hipStream_t stream) {
    const float* inputs = (const float*)d_in[0];
    const float* pmask  = (const float*)d_in[1];
    const float* cpw    = (const float*)d_in[2];
    const float* cpb    = (const float*)d_in[3];
    const float* dww    = (const float*)d_in[4];
    const float* dwb    = (const float*)d_in[5];
    const float* pww    = (const float*)d_in[6];
    const float* pwb    = (const float*)d_in[7];
    const float* g1     = (const float*)d_in[8];
    const float* b1     = (const float*)d_in[9];
    const float* g2     = (const float*)d_in[10];
    const float* b2     = (const float*)d_in[11];
    const float* pjw    = (const float*)d_in[12];
    const float* pjb    = (const float*)d_in[13];
    float* out  = (float*)d_out;
    float* part = (float*)d_ws;

    const size_t smem = (size_t)SMEM_FLOATS * sizeof(float);
    hipFuncSetAttribute(reinterpret_cast<const void*>(vits_fused),
                        hipFuncAttributeMaxDynamicSharedMemorySize, (int)smem);
    vits_fused<<<NB*NTB, THREADS, smem, stream>>>(inputs, pmask, cpw, cpb, dww, dwb,
                                                  pww, pwb, g1, b1, g2, b2, pjw, pjb,
                                                  out, part);
    ld_reduce<<<1, 64, 0, stream>>>(part, out + (size_t)NB*2*NT);
}

// Round 4
// 686.338 us; speedup vs baseline: 5.0305x; 1.2504x over previous
//
#include <hip/hip_runtime.h>
#include <hip/hip_bf16.h>
#include <math.h>

#define HIDDEN 192
#define NBINS 10
#define PROJ 29          // 3*NBINS-1
#define TAILF 5.0f
#define NLAYERS 3
#define NB 64
#define NT 2048
#define TT 64
#define HALO 13
#define COLS (TT + 2*HALO)   // 90
#define CP 91                 // padded f32 row stride (odd dwords)
#define NPAD 96               // GEMM N padded
#define YS 194                // Yt bf16 row stride (97 dwords, odd -> conflict-free cols)
#define NTB (NT/TT)           // 32
#define LN_EPS 1e-5f
#define MIN_BIN 1e-3f
#define MIN_DERF 1e-3f
#define INV_SQRTF 0.07216878364870323f   // 1/sqrt(192)
#define THREADS 768
#define NWAVES 12

// LDS layout (float units)
#define OFF_H 0
#define OFF_YT (HIDDEN*CP)                    // 17472
#define YT_FLOATS (NPAD*YS/2)                 // 9312
#define OFF_MK (OFF_YT + YT_FLOATS)           // 26784
#define OFF_FV (OFF_MK + COLS)
#define OFF_LNP (OFF_FV + COLS)               // 26964: [L][{g1,b1,g2,b2}][192]
#define SMEM_FLOATS (OFF_LNP + NLAYERS*4*HIDDEN)  // 29268 floats = 117072 B
#define OFF_PB OFF_YT                         // projection buffer reuses Yt
#define OFF_SC OFF_H                          // spline scratch reuses hb

#define WS_PART_BYTES 8192
#define WBF_ELEMS (NLAYERS*HIDDEN*HIDDEN)

typedef __attribute__((ext_vector_type(8))) short bf16x8;
typedef __attribute__((ext_vector_type(4))) float f32x4;

__device__ __forceinline__ unsigned short f2bf(float f) {
    __hip_bfloat16 h = __float2bfloat16(f);
    return __builtin_bit_cast(unsigned short, h);
}
__device__ __forceinline__ unsigned packbf(float lo, float hi_) {
    return (unsigned)f2bf(lo) | ((unsigned)f2bf(hi_) << 16);
}
__device__ __forceinline__ float bf2f_lo(unsigned u) {
    union { unsigned u; float f; } c; c.u = u << 16; return c.f;
}
__device__ __forceinline__ float bf2f_hi(unsigned u) {
    union { unsigned u; float f; } c; c.u = u & 0xffff0000u; return c.f;
}

// exact GELU via A&S 7.1.26 rational erf (|err| < 1.5e-7), hw rcp/exp2
__device__ __forceinline__ float gelu_fast(float x) {
    const float az = fabsf(x) * 0.7071067811865476f;
    const float t  = __builtin_amdgcn_rcpf(fmaf(0.3275911f, az, 1.0f));
    float p = fmaf(1.061405429f, t, -1.453152027f);
    p = fmaf(p, t, 1.421413741f);
    p = fmaf(p, t, -0.284496736f);
    p = fmaf(p, t, 0.254829592f);
    p = p * t;
    const float e  = __builtin_amdgcn_exp2f(az*az*(-1.4426950408889634f));
    const float er = fmaf(-p, e, 1.0f);            // erf(|x|/sqrt2)
    const float se = (x >= 0.0f) ? er : -er;
    return 0.5f * x * (1.0f + se);
}
__device__ __forceinline__ float softplus_f(float x) {
    return (x > 20.0f) ? x : log1pf(expf(x));
}
__device__ __forceinline__ float wave_sum(float v) {
    #pragma unroll
    for (int o = 32; o > 0; o >>= 1) v += __shfl_xor(v, o, 64);
    return v;
}

// LN over channels for one column (8 lanes/col, 24 ch/lane) + GELU.
// toYt: write result back to Yt (bf16); dead cols -> zeros (skip math).
// else: residual-add into hb (f32), predicated on live col range.
__device__ __forceinline__ void ln_pass(unsigned short* yt, float* hb,
                                        const float* g, const float* b,
                                        int tid, int jlo, int jhi, bool toYt) {
    const int col = tid >> 3, q = tid & 7;
    const int c0 = q * 24;
    unsigned short* row = yt + col * YS;
    unsigned* wp = (unsigned*)(row + c0);
    if (toYt && (col < jlo || col >= jhi)) {
        #pragma unroll
        for (int i = 0; i < 12; ++i) wp[i] = 0u;
        return;
    }
    const unsigned* rp = (const unsigned*)(row + c0);
    float v[24];
    float s = 0.0f, ss = 0.0f;
    #pragma unroll
    for (int i = 0; i < 12; ++i) {
        unsigned u = rp[i];
        float a = bf2f_lo(u), c = bf2f_hi(u);
        v[2*i] = a; v[2*i+1] = c;
        s += a + c; ss += a*a + c*c;
    }
    s  += __shfl_xor(s, 1, 64);  s  += __shfl_xor(s, 2, 64);  s  += __shfl_xor(s, 4, 64);
    ss += __shfl_xor(ss, 1, 64); ss += __shfl_xor(ss, 2, 64); ss += __shfl_xor(ss, 4, 64);
    const float mu  = s * (1.0f/HIDDEN);
    const float var = fmaxf(ss * (1.0f/HIDDEN) - mu*mu, 0.0f);
    const float rs  = rsqrtf(var + LN_EPS);

    float gv[24], bv[24];
    #pragma unroll
    for (int i = 0; i < 6; ++i) {
        float4 t = *(const float4*)(g + c0 + 4*i);
        gv[4*i] = t.x; gv[4*i+1] = t.y; gv[4*i+2] = t.z; gv[4*i+3] = t.w;
        float4 u = *(const float4*)(b + c0 + 4*i);
        bv[4*i] = u.x; bv[4*i+1] = u.y; bv[4*i+2] = u.z; bv[4*i+3] = u.w;
    }
    if (toYt) {
        #pragma unroll
        for (int i = 0; i < 12; ++i) {
            float r0 = gelu_fast((v[2*i]   - mu)*rs*gv[2*i]   + bv[2*i]);
            float r1 = gelu_fast((v[2*i+1] - mu)*rs*gv[2*i+1] + bv[2*i+1]);
            wp[i] = packbf(r0, r1);
        }
    } else {
        if (col >= jlo && col < jhi) {
            #pragma unroll
            for (int i = 0; i < 24; ++i) {
                float r = gelu_fast((v[i] - mu)*rs*gv[i] + bv[i]);
                hb[(c0 + i)*CP + col] += r;
            }
        }
    }
}

__global__ void wconv_kernel(const float* __restrict__ pww, unsigned short* __restrict__ wbf) {
    int i = blockIdx.x * 1024 + threadIdx.x;
    if (i < WBF_ELEMS) wbf[i] = f2bf(pww[i]);
}

__global__ __launch_bounds__(THREADS) void vits_fused(
    const float* __restrict__ inputs, const float* __restrict__ pmask,
    const float* __restrict__ cpw, const float* __restrict__ cpb,
    const float* __restrict__ dww, const float* __restrict__ dwb,
    const float* __restrict__ pww, const float* __restrict__ pwb,
    const float* __restrict__ g1, const float* __restrict__ b1,
    const float* __restrict__ g2, const float* __restrict__ b2,
    const float* __restrict__ pjw, const float* __restrict__ pjb,
    float* __restrict__ out, float* __restrict__ part,
    const unsigned short* __restrict__ wbf, int preW)
{
    extern __shared__ float sm[];
    float* hb = sm + OFF_H;
    unsigned short* yt = (unsigned short*)(sm + OFF_YT);
    float* mk = sm + OFF_MK;
    float* fv = sm + OFF_FV;
    float* lnp = sm + OFF_LNP;

    const int tid = threadIdx.x;
    const int lane = tid & 63;
    const int wid = tid >> 6;
    const int wu  = __builtin_amdgcn_readfirstlane(wid);
    const int b  = blockIdx.x / NTB;
    const int tb = blockIdx.x % NTB;
    const int t0 = tb*TT - HALO;

    // ---- stage LN params into LDS: [L][{g1,b1,g2,b2}][192] ----
    for (int i = tid; i < NLAYERS*4*HIDDEN; i += THREADS) {
        const int L = i / (4*HIDDEN);
        const int r = i - L*4*HIDDEN;
        const int which = r / HIDDEN;
        const int c = r - which*HIDDEN;
        const float* src = (which == 0) ? g1 : (which == 1) ? b1 : (which == 2) ? g2 : b2;
        lnp[i] = src[L*HIDDEN + c];
    }

    // ---- load first-channel + mask tiles (zero outside [0,T)) ----
    for (int j = tid; j < COLS; j += THREADS) {
        int t = t0 + j;
        bool in = (t >= 0) && (t < NT);
        fv[j] = in ? inputs[(size_t)b*2*NT + t] : 0.0f;
        mk[j] = in ? pmask[(size_t)b*NT + t] : 0.0f;
    }
    __syncthreads();

    // ---- h = conv_pre (outer product, HALF==1), row-per-wave ----
    for (int c = wu; c < HIDDEN; c += NWAVES) {
        const float wv = cpw[c], bv = cpb[c];
        float* hrow = hb + c*CP;
        for (int j = lane; j < COLS; j += 64)
            hrow[j] = wv*fv[j] + bv;
    }
    __syncthreads();

    const int dils[NLAYERS]  = {1, 3, 9};
    const int mouts[NLAYERS] = {1, 4, 13};

    const int l15 = lane & 15, hi = lane >> 4;
    const int mgrp = wu & 3;    // 0..3 -> M offset mgrp*48
    const int ngrp = wu >> 2;   // 0..2 -> N offset ngrp*32

    for (int L = 0; L < NLAYERS; ++L) {
        const int dil = dils[L];
        const int jlo = mouts[L], jhi = COLS - mouts[L];

        // ---- depthwise dilated conv + bias -> Yt (bf16, transposed), live cols only ----
        for (int c = wu; c < HIDDEN; c += NWAVES) {
            const float* w = dww + ((size_t)L*HIDDEN + c)*3;
            const float w0 = w[0], w1 = w[1], w2 = w[2];
            const float bv = dwb[L*HIDDEN + c];
            const float* hrow = hb + c*CP;
            for (int jj = jlo + lane; jj < jhi; jj += 64) {
                float v = bv + w0*hrow[jj-dil]*mk[jj-dil]
                             + w1*hrow[jj    ]*mk[jj    ]
                             + w2*hrow[jj+dil]*mk[jj+dil];
                yt[jj*YS + c] = f2bf(v);
            }
        }
        __syncthreads();

        // ---- LN1 + GELU in place on Yt (dead cols zeroed) ----
        ln_pass(yt, hb, lnp + (L*4+0)*HIDDEN, lnp + (L*4+1)*HIDDEN, tid, jlo, jhi, true);
        __syncthreads();

        // ---- pointwise 192x192 GEMM via MFMA (bf16 in, f32 acc) ----
        {
            bf16x8 Bf[2][6];
            #pragma unroll
            for (int nt = 0; nt < 2; ++nt) {
                const int n = ngrp*32 + nt*16 + l15;
                const unsigned short* yr = yt + n*YS;
                #pragma unroll
                for (int ks = 0; ks < 6; ++ks) {
                    const unsigned* p = (const unsigned*)(yr + ks*32 + hi*8);
                    union { unsigned u[4]; bf16x8 v; } cv;
                    cv.u[0] = p[0]; cv.u[1] = p[1]; cv.u[2] = p[2]; cv.u[3] = p[3];
                    Bf[nt][ks] = cv.v;
                }
            }
            f32x4 acc[3][2];
            #pragma unroll
            for (int mt = 0; mt < 3; ++mt)
                #pragma unroll
                for (int nt = 0; nt < 2; ++nt)
                    acc[mt][nt] = (f32x4){0.0f, 0.0f, 0.0f, 0.0f};

            if (preW) {
                const unsigned short* wbl = wbf + (size_t)L*HIDDEN*HIDDEN;
                #pragma unroll
                for (int mt = 0; mt < 3; ++mt) {
                    const int m = mgrp*48 + mt*16 + l15;
                    const unsigned short* wr = wbl + (size_t)m*HIDDEN + hi*8;
                    #pragma unroll
                    for (int ks = 0; ks < 6; ++ks) {
                        bf16x8 a = *(const bf16x8*)(wr + ks*32);
                        acc[mt][0] = __builtin_amdgcn_mfma_f32_16x16x32_bf16(a, Bf[0][ks], acc[mt][0], 0, 0, 0);
                        acc[mt][1] = __builtin_amdgcn_mfma_f32_16x16x32_bf16(a, Bf[1][ks], acc[mt][1], 0, 0, 0);
                    }
                }
            } else {
                const float* wlayer = pww + (size_t)L*HIDDEN*HIDDEN;
                #pragma unroll
                for (int mt = 0; mt < 3; ++mt) {
                    const int m = mgrp*48 + mt*16 + l15;
                    const float* wr = wlayer + (size_t)m*HIDDEN + hi*8;
                    #pragma unroll
                    for (int ks = 0; ks < 6; ++ks) {
                        float4 a0 = *(const float4*)(wr + ks*32);
                        float4 a1 = *(const float4*)(wr + ks*32 + 4);
                        bf16x8 a;
                        a[0] = (short)f2bf(a0.x); a[1] = (short)f2bf(a0.y);
                        a[2] = (short)f2bf(a0.z); a[3] = (short)f2bf(a0.w);
                        a[4] = (short)f2bf(a1.x); a[5] = (short)f2bf(a1.y);
                        a[6] = (short)f2bf(a1.z); a[7] = (short)f2bf(a1.w);
                        acc[mt][0] = __builtin_amdgcn_mfma_f32_16x16x32_bf16(a, Bf[0][ks], acc[mt][0], 0, 0, 0);
                        acc[mt][1] = __builtin_amdgcn_mfma_f32_16x16x32_bf16(a, Bf[1][ks], acc[mt][1], 0, 0, 0);
                    }
                }
            }
            __syncthreads();   // all Yt reads complete before overwrite

            // bias + write z back over Yt (bf16, transposed)
            #pragma unroll
            for (int mt = 0; mt < 3; ++mt) {
                const int mrow = mgrp*48 + mt*16 + hi*4;
                float4 bias = *(const float4*)(pwb + L*HIDDEN + mrow);
                #pragma unroll
                for (int nt = 0; nt < 2; ++nt) {
                    const int n = ngrp*32 + nt*16 + l15;
                    unsigned* zr = (unsigned*)(yt + n*YS + mrow);
                    f32x4 v = acc[mt][nt];
                    zr[0] = packbf(v[0] + bias.x, v[1] + bias.y);
                    zr[1] = packbf(v[2] + bias.z, v[3] + bias.w);
                }
            }
        }
        __syncthreads();

        // ---- LN2 + GELU + residual into hb (f32) ----
        ln_pass(yt, hb, lnp + (L*4+2)*HIDDEN, lnp + (L*4+3)*HIDDEN, tid, jlo, jhi, false);
        __syncthreads();
    }

    // ---- projection: p[o][j] = proj_w @ (h*mask) + proj_b, o<29, j<64 ----
    float* pb = sm + OFF_PB;   // [TT][33]
    for (int idx = tid; idx < PROJ*TT; idx += THREADS) {
        int o = __builtin_amdgcn_readfirstlane(idx >> 6);  // uniform per wave
        int j = idx & 63;
        int jj = HALO + j;
        const float* w = pjw + (size_t)o*HIDDEN;
        const float mkv = mk[jj];
        float acc = 0.0f;
        #pragma unroll 4
        for (int c = 0; c < HIDDEN; ++c)
            acc = fmaf(w[c], hb[c*CP + jj], acc);
        pb[j*33 + o] = acc*mkv + pjb[o];
    }
    __syncthreads();

    // ---- spline epilogue: one lane per column (wave 0) ----
    float* sc = sm + OFF_SC;
    if (tid < TT) {
        const int j  = tid;
        const int t  = tb*TT + j;
        const int jj = HALO + j;
        float* S  = sc + j*57;
        float* cw = S;          // 11
        float* ch = S + 11;     // 11
        float* wd = S + 22;     // 10
        float* ht = S + 32;     // 10
        float* dv = S + 42;     // 11

        const float x  = inputs[(size_t)b*2*NT + NT + t];
        const float mv = mk[jj];

        {
            float u[NBINS]; float m = -1e30f;
            #pragma unroll
            for (int k = 0; k < NBINS; ++k) { u[k] = pb[j*33 + k]*INV_SQRTF; m = fmaxf(m, u[k]); }
            float se = 0.0f;
            #pragma unroll
            for (int k = 0; k < NBINS; ++k) { u[k] = expf(u[k] - m); se += u[k]; }
            float inv = 1.0f/se, csum = 0.0f;
            cw[0] = -TAILF;
            #pragma unroll
            for (int k = 0; k < NBINS; ++k) {
                float wk = MIN_BIN + (1.0f - NBINS*MIN_BIN)*u[k]*inv;
                csum += wk;
                cw[k+1] = 2.0f*TAILF*csum - TAILF;
            }
            cw[NBINS] = TAILF;
            #pragma unroll
            for (int k = 0; k < NBINS; ++k) wd[k] = cw[k+1] - cw[k];
        }
        {
            float u[NBINS]; float m = -1e30f;
            #pragma unroll
            for (int k = 0; k < NBINS; ++k) { u[k] = pb[j*33 + 10 + k]*INV_SQRTF; m = fmaxf(m, u[k]); }
            float se = 0.0f;
            #pragma unroll
            for (int k = 0; k < NBINS; ++k) { u[k] = expf(u[k] - m); se += u[k]; }
            float inv = 1.0f/se, csum = 0.0f;
            ch[0] = -TAILF;
            #pragma unroll
            for (int k = 0; k < NBINS; ++k) {
                float wk = MIN_BIN + (1.0f - NBINS*MIN_BIN)*u[k]*inv;
                csum += wk;
                ch[k+1] = 2.0f*TAILF*csum - TAILF;
            }
            ch[NBINS] = TAILF;
            #pragma unroll
            for (int k = 0; k < NBINS; ++k) ht[k] = ch[k+1] - ch[k];
        }
        {
            const float cpad = logf(expf(1.0f - MIN_DERF) - 1.0f);
            float edge = MIN_DERF + softplus_f(cpad);
            dv[0] = edge;
            #pragma unroll
            for (int k = 0; k < NBINS-1; ++k) dv[k+1] = MIN_DERF + softplus_f(pb[j*33 + 2*NBINS + k]);
            dv[NBINS] = edge;
        }

        const float xi = fminf(fmaxf(x, -TAILF), TAILF);
        int cnt = 0;
        #pragma unroll
        for (int k = 0; k <= NBINS; ++k) {
            float bl = cw[k] + ((k == NBINS) ? 1e-6f : 0.0f);
            cnt += (xi >= bl) ? 1 : 0;
        }
        int bi = cnt - 1;
        bi = (bi < 0) ? 0 : ((bi > NBINS-1) ? NBINS-1 : bi);

        const float in_cw = cw[bi], in_w = wd[bi];
        const float in_ch = ch[bi], in_h = ht[bi];
        const float in_d  = ht[bi]/wd[bi];
        const float dA = dv[bi], dB = dv[bi+1];
        const float i1 = dA + dB - 2.0f*in_d;
        const float th = (xi - in_cw)/in_w;
        const float t1m = th*(1.0f - th);
        const float den = in_d + i1*t1m;
        const float outv = in_ch + in_h*(in_d*th*th + dA*t1m)/den;
        const float omt = 1.0f - th;
        const float dnum = in_d*in_d*(dB*th*th + 2.0f*in_d*t1m + dA*omt*omt);
        const float lad = logf(dnum) - 2.0f*logf(den);

        const bool inside = (x >= -TAILF) && (x <= TAILF);
        const float sec  = inside ? outv : x;
        const float ladm = (inside ? lad : 0.0f) * mv;

        out[(size_t)b*2*NT + t]      = fv[jj]*mv;
        out[(size_t)b*2*NT + NT + t] = sec*mv;

        float tot = wave_sum(ladm);
        if (lane == 0) part[b*NTB + tb] = tot;
    }
}

__global__ void ld_reduce(const float* __restrict__ part, float* __restrict__ ld) {
    int b = threadIdx.x;
    if (b < NB) {
        float s = 0.0f;
        for (int k = 0; k < NTB; ++k) s += part[b*NTB + k];
        ld[b] = s;
    }
}

extern "C" void kernel_launch(void* const* d_in, const int* in_sizes, int n_in,
                              void* d_out, int out_size, void* d_ws, size_t ws_size,
                              hipStream_t stream) {
    const float* inputs = (const float*)d_in[0];
    const float* pmask  = (const float*)d_in[1];
    const float* cpw    = (const float*)d_in[2];
    const float* cpb    = (const float*)d_in[3];
    const float* dww    = (const float*)d_in[4];
    const float* dwb    = (const float*)d_in[5];
    const float* pww    = (const float*)d_in[6];
    const float* pwb    = (const float*)d_in[7];
    const float* g1     = (const float*)d_in[8];
    const float* b1     = (const float*)d_in[9];
    const float* g2     = (const float*)d_in[10];
    const float* b2     = (const float*)d_in[11];
    const float* pjw    = (const float*)d_in[12];
    const float* pjb    = (const float*)d_in[13];
    float* out  = (float*)d_out;
    float* part = (float*)d_ws;

    const size_t need = WS_PART_BYTES + (size_t)WBF_ELEMS*2;
    const int preW = (ws_size >= need) ? 1 : 0;
    unsigned short* wbf = (unsigned short*)((char*)d_ws + WS_PART_BYTES);

    if (preW) {
        wconv_kernel<<<(WBF_ELEMS + 1023)/1024, 1024, 0, stream>>>(pww, wbf);
    }

    const size_t smem = (size_t)SMEM_FLOATS * sizeof(float);
    hipFuncSetAttribute(reinterpret_cast<const void*>(vits_fused),
                        hipFuncAttributeMaxDynamicSharedMemorySize, (int)smem);
    vits_fused<<<NB*NTB, THREADS, smem, stream>>>(inputs, pmask, cpw, cpb, dww, dwb,
                                                  pww, pwb, g1, b1, g2, b2, pjw, pjb,
                                                  out, part, wbf, preW);
    ld_reduce<<<1, 64, 0, stream>>>(part, out + (size_t)NB*2*NT);
}

// Round 5
// 570.960 us; speedup vs baseline: 6.0470x; 1.2021x over previous
//
#include <hip/hip_runtime.h>
#include <hip/hip_bf16.h>
#include <math.h>

#define HIDDEN 192
#define NBINS 10
#define PROJ 29          // 3*NBINS-1
#define TAILF 5.0f
#define NLAYERS 3
#define NB 64
#define NT 2048
#define TT 64
#define HALO 13
#define COLS (TT + 2*HALO)   // 90
#define HS 94                 // hb bf16 row stride (47 dwords, odd -> conflict-free cols)
#define NPAD 96               // GEMM N padded
#define YS 194                // Yt bf16 row stride (97 dwords, odd)
#define NTB (NT/TT)           // 32
#define LN_EPS 1e-5f
#define MIN_BIN 1e-3f
#define MIN_DERF 1e-3f
#define INV_SQRTF 0.07216878364870323f   // 1/sqrt(192)
#define THREADS 768
#define NWAVES 12

// LDS layout: shorts first, then f32 section
#define HB_SHORTS (HIDDEN*HS)                 // 18048
#define YT_SHORTS (NPAD*YS)                   // 18624
#define OFF_F32 ((HB_SHORTS + YT_SHORTS)/2)   // float index: 18336
#define N_LNP (NLAYERS*2*HIDDEN)              // 1152 packed (g,b) dwords
#define SMEM_FLOATS (OFF_F32 + 90 + 90 + N_LNP)   // 19668 floats = 78672 B

#define WS_PART_BYTES 8192
#define WBF_ELEMS (NLAYERS*HIDDEN*HIDDEN)

typedef __attribute__((ext_vector_type(8))) short bf16x8;
typedef __attribute__((ext_vector_type(4))) float f32x4;

__device__ __forceinline__ unsigned short f2bf(float f) {
    __hip_bfloat16 h = __float2bfloat16(f);
    return __builtin_bit_cast(unsigned short, h);
}
__device__ __forceinline__ unsigned packbf(float lo, float hi_) {
    return (unsigned)f2bf(lo) | ((unsigned)f2bf(hi_) << 16);
}
__device__ __forceinline__ float bf2f_lo(unsigned u) {
    union { unsigned u; float f; } c; c.u = u << 16; return c.f;
}
__device__ __forceinline__ float bf2f_hi(unsigned u) {
    union { unsigned u; float f; } c; c.u = u & 0xffff0000u; return c.f;
}
__device__ __forceinline__ float bfs(unsigned short s) {
    union { unsigned u; float f; } c; c.u = ((unsigned)s) << 16; return c.f;
}

// exact GELU via A&S 7.1.26 rational erf (|err| < 1.5e-7), hw rcp/exp2
__device__ __forceinline__ float gelu_fast(float x) {
    const float az = fabsf(x) * 0.7071067811865476f;
    const float t  = __builtin_amdgcn_rcpf(fmaf(0.3275911f, az, 1.0f));
    float p = fmaf(1.061405429f, t, -1.453152027f);
    p = fmaf(p, t, 1.421413741f);
    p = fmaf(p, t, -0.284496736f);
    p = fmaf(p, t, 0.254829592f);
    p = p * t;
    const float e  = __builtin_amdgcn_exp2f(az*az*(-1.4426950408889634f));
    const float er = fmaf(-p, e, 1.0f);            // erf(|x|/sqrt2)
    const float se = (x >= 0.0f) ? er : -er;
    return 0.5f * x * (1.0f + se);
}
__device__ __forceinline__ float softplus_f(float x) {
    return (x > 20.0f) ? x : log1pf(expf(x));
}
__device__ __forceinline__ float wave_sum(float v) {
    #pragma unroll
    for (int o = 32; o > 0; o >>= 1) v += __shfl_xor(v, o, 64);
    return v;
}

// LN over channels for one column (8 lanes/col, 24 ch/lane) + GELU.
// toYt: write back to Yt (bf16); dead cols -> zeros. else: residual-add into hb (bf16).
__device__ __forceinline__ void ln_pass(unsigned short* yt, unsigned short* hbs,
                                        const unsigned* gb,
                                        int tid, int jlo, int jhi, bool toYt) {
    const int col = tid >> 3, q = tid & 7;
    const int c0 = q * 24;
    unsigned short* row = yt + col * YS;
    unsigned* wp = (unsigned*)(row + c0);
    if (toYt && (col < jlo || col >= jhi)) {
        #pragma unroll
        for (int i = 0; i < 12; ++i) wp[i] = 0u;
        return;
    }
    const unsigned* rp = (const unsigned*)(row + c0);
    float v[24];
    float s = 0.0f, ss = 0.0f;
    #pragma unroll
    for (int i = 0; i < 12; ++i) {
        unsigned u = rp[i];
        float a = bf2f_lo(u), c = bf2f_hi(u);
        v[2*i] = a; v[2*i+1] = c;
        s += a + c; ss += a*a + c*c;
    }
    s  += __shfl_xor(s, 1, 64);  s  += __shfl_xor(s, 2, 64);  s  += __shfl_xor(s, 4, 64);
    ss += __shfl_xor(ss, 1, 64); ss += __shfl_xor(ss, 2, 64); ss += __shfl_xor(ss, 4, 64);
    const float mu  = s * (1.0f/HIDDEN);
    const float var = fmaxf(ss * (1.0f/HIDDEN) - mu*mu, 0.0f);
    const float rs  = rsqrtf(var + LN_EPS);

    float gv[24], bv[24];
    #pragma unroll
    for (int i = 0; i < 24; ++i) {
        unsigned u = gb[c0 + i];
        gv[i] = bf2f_lo(u); bv[i] = bf2f_hi(u);
    }
    if (toYt) {
        #pragma unroll
        for (int i = 0; i < 12; ++i) {
            float r0 = gelu_fast((v[2*i]   - mu)*rs*gv[2*i]   + bv[2*i]);
            float r1 = gelu_fast((v[2*i+1] - mu)*rs*gv[2*i+1] + bv[2*i+1]);
            wp[i] = packbf(r0, r1);
        }
    } else {
        if (col >= jlo && col < jhi) {
            #pragma unroll
            for (int i = 0; i < 24; ++i) {
                float r = gelu_fast((v[i] - mu)*rs*gv[i] + bv[i]);
                const int idx = (c0 + i)*HS + col;
                hbs[idx] = f2bf(bfs(hbs[idx]) + r);
            }
        }
    }
}

__global__ void wconv_kernel(const float* __restrict__ pww, unsigned short* __restrict__ wbf) {
    int i = blockIdx.x * 1024 + threadIdx.x;
    if (i < WBF_ELEMS) wbf[i] = f2bf(pww[i]);
}

__global__ __launch_bounds__(THREADS) void vits_fused(
    const float* __restrict__ inputs, const float* __restrict__ pmask,
    const float* __restrict__ cpw, const float* __restrict__ cpb,
    const float* __restrict__ dww, const float* __restrict__ dwb,
    const float* __restrict__ pww, const float* __restrict__ pwb,
    const float* __restrict__ g1, const float* __restrict__ b1,
    const float* __restrict__ g2, const float* __restrict__ b2,
    const float* __restrict__ pjw, const float* __restrict__ pjb,
    float* __restrict__ out, float* __restrict__ part,
    const unsigned short* __restrict__ wbf, int preW)
{
    extern __shared__ float sm[];
    unsigned short* hbs = (unsigned short*)sm;
    unsigned short* yt  = hbs + HB_SHORTS;
    float* mk = sm + OFF_F32;
    float* fv = mk + 90;
    unsigned* lnpp = (unsigned*)(fv + 90);   // [L][{ln1,ln2}][192] packed (g,b)

    const int tid = threadIdx.x;
    const int lane = tid & 63;
    const int wid = tid >> 6;
    const int wu  = __builtin_amdgcn_readfirstlane(wid);
    const int b  = blockIdx.x / NTB;
    const int tb = blockIdx.x % NTB;
    const int t0 = tb*TT - HALO;

    // ---- stage packed LN params into LDS ----
    for (int i = tid; i < N_LNP; i += THREADS) {
        const int L = i / (2*HIDDEN);
        const int r = i - L*2*HIDDEN;
        const int which = r / HIDDEN;
        const int c = r - which*HIDDEN;
        const float* gp = which ? g2 : g1;
        const float* bp = which ? b2 : b1;
        lnpp[i] = packbf(gp[L*HIDDEN + c], bp[L*HIDDEN + c]);
    }

    // ---- load first-channel + mask tiles (zero outside [0,T)) ----
    for (int j = tid; j < COLS; j += THREADS) {
        int t = t0 + j;
        bool in = (t >= 0) && (t < NT);
        fv[j] = in ? inputs[(size_t)b*2*NT + t] : 0.0f;
        mk[j] = in ? pmask[(size_t)b*NT + t] : 0.0f;
    }
    __syncthreads();

    // ---- h = conv_pre (outer product, HALF==1), row-per-wave ----
    for (int c = wu; c < HIDDEN; c += NWAVES) {
        const float wv = cpw[c], bv = cpb[c];
        unsigned short* hrow = hbs + c*HS;
        for (int j = lane; j < COLS; j += 64)
            hrow[j] = f2bf(wv*fv[j] + bv);
    }
    __syncthreads();

    const int dils[NLAYERS]  = {1, 3, 9};
    const int mouts[NLAYERS] = {1, 4, 13};

    const int l15 = lane & 15, hi = lane >> 4;
    const int mgrp = wu & 3;    // 0..3 -> M offset mgrp*48
    const int ngrp = wu >> 2;   // 0..2 -> N offset ngrp*32

    for (int L = 0; L < NLAYERS; ++L) {
        const int dil = dils[L];
        const int jlo = mouts[L], jhi = COLS - mouts[L];

        // ---- depthwise dilated conv + bias -> Yt (bf16, transposed) ----
        {
            const int jA = jlo + lane;               // always < jhi (nc >= 64)
            const int jB = jlo + 64 + lane;
            const bool actB = jB < jhi;
            const float mA0 = mk[jA-dil], mA1 = mk[jA], mA2 = mk[jA+dil];
            float mB0 = 0.f, mB1 = 0.f, mB2 = 0.f;
            if (actB) { mB0 = mk[jB-dil]; mB1 = mk[jB]; mB2 = mk[jB+dil]; }
            for (int c = wu; c < HIDDEN; c += NWAVES) {
                const float* w = dww + ((size_t)L*HIDDEN + c)*3;
                const float w0 = w[0], w1 = w[1], w2 = w[2];
                const float bv = dwb[L*HIDDEN + c];
                const unsigned short* hrow = hbs + c*HS;
                float vA = bv + w0*bfs(hrow[jA-dil])*mA0
                              + w1*bfs(hrow[jA    ])*mA1
                              + w2*bfs(hrow[jA+dil])*mA2;
                yt[jA*YS + c] = f2bf(vA);
                if (actB) {
                    float vB = bv + w0*bfs(hrow[jB-dil])*mB0
                                  + w1*bfs(hrow[jB    ])*mB1
                                  + w2*bfs(hrow[jB+dil])*mB2;
                    yt[jB*YS + c] = f2bf(vB);
                }
            }
        }
        __syncthreads();

        // ---- LN1 + GELU in place on Yt (dead cols zeroed) ----
        ln_pass(yt, hbs, lnpp + (L*2+0)*HIDDEN, tid, jlo, jhi, true);
        __syncthreads();

        // ---- pointwise 192x192 GEMM via MFMA (bf16 in, f32 acc) ----
        {
            bf16x8 Bf[2][6];
            #pragma unroll
            for (int nt = 0; nt < 2; ++nt) {
                const int n = ngrp*32 + nt*16 + l15;
                const unsigned short* yr = yt + n*YS;
                #pragma unroll
                for (int ks = 0; ks < 6; ++ks) {
                    const unsigned* p = (const unsigned*)(yr + ks*32 + hi*8);
                    union { unsigned u[4]; bf16x8 v; } cv;
                    cv.u[0] = p[0]; cv.u[1] = p[1]; cv.u[2] = p[2]; cv.u[3] = p[3];
                    Bf[nt][ks] = cv.v;
                }
            }
            f32x4 acc[3][2];
            #pragma unroll
            for (int mt = 0; mt < 3; ++mt)
                #pragma unroll
                for (int nt = 0; nt < 2; ++nt)
                    acc[mt][nt] = (f32x4){0.0f, 0.0f, 0.0f, 0.0f};

            if (preW) {
                const unsigned short* wbl = wbf + (size_t)L*HIDDEN*HIDDEN;
                #pragma unroll
                for (int mt = 0; mt < 3; ++mt) {
                    const int m = mgrp*48 + mt*16 + l15;
                    const unsigned short* wr = wbl + (size_t)m*HIDDEN + hi*8;
                    #pragma unroll
                    for (int ks = 0; ks < 6; ++ks) {
                        bf16x8 a = *(const bf16x8*)(wr + ks*32);
                        acc[mt][0] = __builtin_amdgcn_mfma_f32_16x16x32_bf16(a, Bf[0][ks], acc[mt][0], 0, 0, 0);
                        acc[mt][1] = __builtin_amdgcn_mfma_f32_16x16x32_bf16(a, Bf[1][ks], acc[mt][1], 0, 0, 0);
                    }
                }
            } else {
                const float* wlayer = pww + (size_t)L*HIDDEN*HIDDEN;
                #pragma unroll
                for (int mt = 0; mt < 3; ++mt) {
                    const int m = mgrp*48 + mt*16 + l15;
                    const float* wr = wlayer + (size_t)m*HIDDEN + hi*8;
                    #pragma unroll
                    for (int ks = 0; ks < 6; ++ks) {
                        float4 a0 = *(const float4*)(wr + ks*32);
                        float4 a1 = *(const float4*)(wr + ks*32 + 4);
                        bf16x8 a;
                        a[0] = (short)f2bf(a0.x); a[1] = (short)f2bf(a0.y);
                        a[2] = (short)f2bf(a0.z); a[3] = (short)f2bf(a0.w);
                        a[4] = (short)f2bf(a1.x); a[5] = (short)f2bf(a1.y);
                        a[6] = (short)f2bf(a1.z); a[7] = (short)f2bf(a1.w);
                        acc[mt][0] = __builtin_amdgcn_mfma_f32_16x16x32_bf16(a, Bf[0][ks], acc[mt][0], 0, 0, 0);
                        acc[mt][1] = __builtin_amdgcn_mfma_f32_16x16x32_bf16(a, Bf[1][ks], acc[mt][1], 0, 0, 0);
                    }
                }
            }
            __syncthreads();   // all Yt reads complete before overwrite

            // bias + write z back over Yt (bf16, transposed)
            #pragma unroll
            for (int mt = 0; mt < 3; ++mt) {
                const int mrow = mgrp*48 + mt*16 + hi*4;
                float4 bias = *(const float4*)(pwb + L*HIDDEN + mrow);
                #pragma unroll
                for (int nt = 0; nt < 2; ++nt) {
                    const int n = ngrp*32 + nt*16 + l15;
                    unsigned* zr = (unsigned*)(yt + n*YS + mrow);
                    f32x4 v = acc[mt][nt];
                    zr[0] = packbf(v[0] + bias.x, v[1] + bias.y);
                    zr[1] = packbf(v[2] + bias.z, v[3] + bias.w);
                }
            }
        }
        __syncthreads();

        // ---- LN2 + GELU + residual into hb (bf16) ----
        ln_pass(yt, hbs, lnpp + (L*2+1)*HIDDEN, tid, jlo, jhi, false);
        __syncthreads();
    }

    // ---- projection: p[o][j] = proj_w @ (h*mask) + proj_b, o<29, j<64 ----
    float* pb = (float*)yt;   // [TT][33], yt dead
    for (int idx = tid; idx < PROJ*TT; idx += THREADS) {
        int o = __builtin_amdgcn_readfirstlane(idx >> 6);  // uniform per wave
        int j = idx & 63;
        int jj = HALO + j;
        const float* w = pjw + (size_t)o*HIDDEN;
        const float mkv = mk[jj];
        float acc = 0.0f;
        #pragma unroll 4
        for (int c = 0; c < HIDDEN; ++c)
            acc = fmaf(w[c], bfs(hbs[c*HS + jj]), acc);
        pb[j*33 + o] = acc*mkv + pjb[o];
    }
    __syncthreads();

    // ---- spline epilogue: one lane per column (wave 0); scratch over hb ----
    float* sc = sm;   // hb region dead after projection
    if (tid < TT) {
        const int j  = tid;
        const int t  = tb*TT + j;
        const int jj = HALO + j;
        float* S  = sc + j*57;
        float* cw = S;          // 11
        float* ch = S + 11;     // 11
        float* wd = S + 22;     // 10
        float* ht = S + 32;     // 10
        float* dv = S + 42;     // 11

        const float x  = inputs[(size_t)b*2*NT + NT + t];
        const float mv = mk[jj];

        {
            float u[NBINS]; float m = -1e30f;
            #pragma unroll
            for (int k = 0; k < NBINS; ++k) { u[k] = pb[j*33 + k]*INV_SQRTF; m = fmaxf(m, u[k]); }
            float se = 0.0f;
            #pragma unroll
            for (int k = 0; k < NBINS; ++k) { u[k] = expf(u[k] - m); se += u[k]; }
            float inv = 1.0f/se, csum = 0.0f;
            cw[0] = -TAILF;
            #pragma unroll
            for (int k = 0; k < NBINS; ++k) {
                float wk = MIN_BIN + (1.0f - NBINS*MIN_BIN)*u[k]*inv;
                csum += wk;
                cw[k+1] = 2.0f*TAILF*csum - TAILF;
            }
            cw[NBINS] = TAILF;
            #pragma unroll
            for (int k = 0; k < NBINS; ++k) wd[k] = cw[k+1] - cw[k];
        }
        {
            float u[NBINS]; float m = -1e30f;
            #pragma unroll
            for (int k = 0; k < NBINS; ++k) { u[k] = pb[j*33 + 10 + k]*INV_SQRTF; m = fmaxf(m, u[k]); }
            float se = 0.0f;
            #pragma unroll
            for (int k = 0; k < NBINS; ++k) { u[k] = expf(u[k] - m); se += u[k]; }
            float inv = 1.0f/se, csum = 0.0f;
            ch[0] = -TAILF;
            #pragma unroll
            for (int k = 0; k < NBINS; ++k) {
                float wk = MIN_BIN + (1.0f - NBINS*MIN_BIN)*u[k]*inv;
                csum += wk;
                ch[k+1] = 2.0f*TAILF*csum - TAILF;
            }
            ch[NBINS] = TAILF;
            #pragma unroll
            for (int k = 0; k < NBINS; ++k) ht[k] = ch[k+1] - ch[k];
        }
        {
            const float cpad = logf(expf(1.0f - MIN_DERF) - 1.0f);
            float edge = MIN_DERF + softplus_f(cpad);
            dv[0] = edge;
            #pragma unroll
            for (int k = 0; k < NBINS-1; ++k) dv[k+1] = MIN_DERF + softplus_f(pb[j*33 + 2*NBINS + k]);
            dv[NBINS] = edge;
        }

        const float xi = fminf(fmaxf(x, -TAILF), TAILF);
        int cnt = 0;
        #pragma unroll
        for (int k = 0; k <= NBINS; ++k) {
            float bl = cw[k] + ((k == NBINS) ? 1e-6f : 0.0f);
            cnt += (xi >= bl) ? 1 : 0;
        }
        int bi = cnt - 1;
        bi = (bi < 0) ? 0 : ((bi > NBINS-1) ? NBINS-1 : bi);

        const float in_cw = cw[bi], in_w = wd[bi];
        const float in_ch = ch[bi], in_h = ht[bi];
        const float in_d  = ht[bi]/wd[bi];
        const float dA = dv[bi], dB = dv[bi+1];
        const float i1 = dA + dB - 2.0f*in_d;
        const float th = (xi - in_cw)/in_w;
        const float t1m = th*(1.0f - th);
        const float den = in_d + i1*t1m;
        const float outv = in_ch + in_h*(in_d*th*th + dA*t1m)/den;
        const float omt = 1.0f - th;
        const float dnum = in_d*in_d*(dB*th*th + 2.0f*in_d*t1m + dA*omt*omt);
        const float lad = logf(dnum) - 2.0f*logf(den);

        const bool inside = (x >= -TAILF) && (x <= TAILF);
        const float sec  = inside ? outv : x;
        const float ladm = (inside ? lad : 0.0f) * mv;

        out[(size_t)b*2*NT + t]      = fv[jj]*mv;
        out[(size_t)b*2*NT + NT + t] = sec*mv;

        float tot = wave_sum(ladm);
        if (lane == 0) part[b*NTB + tb] = tot;
    }
}

__global__ void ld_reduce(const float* __restrict__ part, float* __restrict__ ld) {
    int b = threadIdx.x;
    if (b < NB) {
        float s = 0.0f;
        for (int k = 0; k < NTB; ++k) s += part[b*NTB + k];
        ld[b] = s;
    }
}

extern "C" void kernel_launch(void* const* d_in, const int* in_sizes, int n_in,
                              void* d_out, int out_size, void* d_ws, size_t ws_size,
                              hipStream_t stream) {
    const float* inputs = (const float*)d_in[0];
    const float* pmask  = (const float*)d_in[1];
    const float* cpw    = (const float*)d_in[2];
    const float* cpb    = (const float*)d_in[3];
    const float* dww    = (const float*)d_in[4];
    const float* dwb    = (const float*)d_in[5];
    const float* pww    = (const float*)d_in[6];
    const float* pwb    = (const float*)d_in[7];
    const float* g1     = (const float*)d_in[8];
    const float* b1     = (const float*)d_in[9];
    const float* g2     = (const float*)d_in[10];
    const float* b2     = (const float*)d_in[11];
    const float* pjw    = (const float*)d_in[12];
    const float* pjb    = (const float*)d_in[13];
    float* out  = (float*)d_out;
    float* part = (float*)d_ws;

    const size_t need = WS_PART_BYTES + (size_t)WBF_ELEMS*2;
    const int preW = (ws_size >= need) ? 1 : 0;
    unsigned short* wbf = (unsigned short*)((char*)d_ws + WS_PART_BYTES);

    if (preW) {
        wconv_kernel<<<(WBF_ELEMS + 1023)/1024, 1024, 0, stream>>>(pww, wbf);
    }

    const size_t smem = (size_t)SMEM_FLOATS * sizeof(float);
    hipFuncSetAttribute(reinterpret_cast<const void*>(vits_fused),
                        hipFuncAttributeMaxDynamicSharedMemorySize, (int)smem);
    vits_fused<<<NB*NTB, THREADS, smem, stream>>>(inputs, pmask, cpw, cpb, dww, dwb,
                                                  pww, pwb, g1, b1, g2, b2, pjw, pjb,
                                                  out, part, wbf, preW);
    ld_reduce<<<1, 64, 0, stream>>>(part, out + (size_t)NB*2*NT);
}